// Round 1
// baseline (174.703 us; speedup 1.0000x reference)
//
#include <hip/hip_runtime.h>
#include <math.h>
#include <stdint.h>

#define C        128
#define KCODES   1024
#define TPB      256
#define ROWS_PB  128                  // rows per block
#define NCHUNK   64                   // codes per LDS chunk
#define NCHUNKS  (KCODES / NCHUNK)    // 16
#define BSTRIDE  272                  // padded row stride (bytes) = 128*2 + 16
#define EPS_TRIG 0.25f

typedef __attribute__((ext_vector_type(8))) short bf16x8_t;
typedef __attribute__((ext_vector_type(4))) float f32x4_t;

static __device__ __forceinline__ uint32_t bf16_rne(float f) {
    uint32_t u = __float_as_uint(f);
    return (u + 0x7FFFu + ((u >> 16) & 1u)) >> 16;
}
static __device__ __forceinline__ float bf16_hi_f(float f) {
    return __uint_as_float(bf16_rne(f) << 16);
}

// ---------------- prep: split codebook into bf16 hi/lo ----------------
__global__ void cb_split_kernel(const float* __restrict__ cb,
                                uint16_t* __restrict__ cbh,
                                uint16_t* __restrict__ cbl) {
    int i = blockIdx.x * blockDim.x + threadIdx.x;
    if (i >= KCODES * C) return;
    float f = cb[i];
    uint32_t h = bf16_rne(f);
    float lo = f - __uint_as_float(h << 16);
    cbh[i] = (uint16_t)h;
    cbl[i] = (uint16_t)bf16_rne(lo);
}

// ---------------- prep: ||c||^2 (R1 arithmetic order) ----------------
__global__ void cbsq_kernel(const float* __restrict__ cb, float* __restrict__ cbsq) {
    const int k = blockIdx.x * blockDim.x + threadIdx.x;
    if (k >= KCODES) return;
    const float4* cp = (const float4*)(cb + (size_t)k * C);
    float sx = 0.f, sy = 0.f, sz = 0.f, sw = 0.f;
    #pragma unroll
    for (int i = 0; i < C / 4; ++i) {
        float4 v = cp[i];
        sx += v.x * v.x; sy += v.y * v.y;
        sz += v.z * v.z; sw += v.w * v.w;
    }
    cbsq[k] = (sx + sy) + (sz + sw);
}

// ---------------- main: MFMA distance + in-block argmin ----------------
#define SLOTS(OP) OP(0,0) OP(0,1) OP(0,2) OP(0,3) OP(1,0) OP(1,1) OP(1,2) OP(1,3)
#define MFMA_BF16 __builtin_amdgcn_mfma_f32_16x16x32_bf16

__global__ __launch_bounds__(TPB, 3)
void vq_mfma_kernel(const float* __restrict__ x,
                    const float* __restrict__ cb,
                    const uint16_t* __restrict__ cbh,
                    const uint16_t* __restrict__ cbl,
                    const float* __restrict__ cq,
                    float* __restrict__ out_codes,
                    float* __restrict__ out_fidx,
                    float* __restrict__ out_idx,
                    float* __restrict__ out_dist,
                    int rows)
{
    __shared__ __align__(16) uint8_t s_buf[NCHUNK * 2 * BSTRIDE];  // 34816 B, also A-stage area
    __shared__ float s_cq[NCHUNK];
    __shared__ float s_v1[ROWS_PB], s_v2[ROWS_PB];
    __shared__ int   s_k1[ROWS_PB], s_k2[ROWS_PB];

    const int t    = threadIdx.x;
    const int lane = t & 63;
    const int w    = t >> 6;       // wave 0..3
    const int ln   = lane & 15;
    const int quad = lane >> 4;
    const int rowblock = blockIdx.x * ROWS_PB;

    // ---- stage x tile -> bf16 HI in s_buf (padded row-major) ----
    #pragma unroll 4
    for (int i = 0; i < 16; ++i) {
        int fid = t + i * TPB;            // float4 id in tile (4096)
        int row = fid >> 5;               // 0..127
        int kq  = fid & 31;               // float4 within row
        int grow = rowblock + row;
        grow = grow < rows ? grow : rows - 1;
        float4 v = ((const float4*)x)[(size_t)grow * 32 + kq];
        uint32_t p0 = bf16_rne(v.x) | (bf16_rne(v.y) << 16);
        uint32_t p1 = bf16_rne(v.z) | (bf16_rne(v.w) << 16);
        *(uint2*)(s_buf + row * BSTRIDE + kq * 8) = make_uint2(p0, p1);
    }
    __syncthreads();

    // ---- A-hi fragments -> registers (live for the whole kernel) ----
    const int arow0 = (w * 32 + ln) * BSTRIDE;        // rowgroup 0
    const int arow1 = (w * 32 + 16 + ln) * BSTRIDE;   // rowgroup 1
    bf16x8_t ah00, ah01, ah02, ah03, ah10, ah11, ah12, ah13;
    ah00 = *(const bf16x8_t*)(s_buf + arow0 + 0 * 64 + quad * 16);
    ah01 = *(const bf16x8_t*)(s_buf + arow0 + 1 * 64 + quad * 16);
    ah02 = *(const bf16x8_t*)(s_buf + arow0 + 2 * 64 + quad * 16);
    ah03 = *(const bf16x8_t*)(s_buf + arow0 + 3 * 64 + quad * 16);
    ah10 = *(const bf16x8_t*)(s_buf + arow1 + 0 * 64 + quad * 16);
    ah11 = *(const bf16x8_t*)(s_buf + arow1 + 1 * 64 + quad * 16);
    ah12 = *(const bf16x8_t*)(s_buf + arow1 + 2 * 64 + quad * 16);
    ah13 = *(const bf16x8_t*)(s_buf + arow1 + 3 * 64 + quad * 16);
    __syncthreads();

    // ---- stage x tile -> bf16 LO ----
    #pragma unroll 4
    for (int i = 0; i < 16; ++i) {
        int fid = t + i * TPB;
        int row = fid >> 5;
        int kq  = fid & 31;
        int grow = rowblock + row;
        grow = grow < rows ? grow : rows - 1;
        float4 v = ((const float4*)x)[(size_t)grow * 32 + kq];
        uint32_t p0 = bf16_rne(v.x - bf16_hi_f(v.x)) | (bf16_rne(v.y - bf16_hi_f(v.y)) << 16);
        uint32_t p1 = bf16_rne(v.z - bf16_hi_f(v.z)) | (bf16_rne(v.w - bf16_hi_f(v.w)) << 16);
        *(uint2*)(s_buf + row * BSTRIDE + kq * 8) = make_uint2(p0, p1);
    }
    __syncthreads();

    bf16x8_t al00, al01, al02, al03, al10, al11, al12, al13;
    al00 = *(const bf16x8_t*)(s_buf + arow0 + 0 * 64 + quad * 16);
    al01 = *(const bf16x8_t*)(s_buf + arow0 + 1 * 64 + quad * 16);
    al02 = *(const bf16x8_t*)(s_buf + arow0 + 2 * 64 + quad * 16);
    al03 = *(const bf16x8_t*)(s_buf + arow0 + 3 * 64 + quad * 16);
    al10 = *(const bf16x8_t*)(s_buf + arow1 + 0 * 64 + quad * 16);
    al11 = *(const bf16x8_t*)(s_buf + arow1 + 1 * 64 + quad * 16);
    al12 = *(const bf16x8_t*)(s_buf + arow1 + 2 * 64 + quad * 16);
    al13 = *(const bf16x8_t*)(s_buf + arow1 + 3 * 64 + quad * 16);
    __syncthreads();

    // ---- per-lane top-2 state (8 row-slots) ----
#define DECL(g,r) float v1_##g##r = INFINITY, v2_##g##r = INFINITY; int k1_##g##r = 0, k2_##g##r = 0;
    SLOTS(DECL)
#undef DECL

    #pragma unroll 1
    for (int chn = 0; chn < NCHUNKS; ++chn) {
        const int kbase = chn * NCHUNK;
        // stage B chunk: 64 codes hi + lo (padded rows)
        #pragma unroll
        for (int i = 0; i < 4; ++i) {
            int uid  = t + i * TPB;          // uint4 id (1024)
            int code = uid >> 4, g = uid & 15;
            uint4 dh = ((const uint4*)cbh)[(size_t)(kbase + code) * 16 + g];
            *(uint4*)(s_buf + code * BSTRIDE + g * 16) = dh;
            uint4 dl = ((const uint4*)cbl)[(size_t)(kbase + code) * 16 + g];
            *(uint4*)(s_buf + NCHUNK * BSTRIDE + code * BSTRIDE + g * 16) = dl;
        }
        if (t < NCHUNK) s_cq[t] = cq[kbase + t];
        __syncthreads();

        const uint8_t* bbase  = s_buf + (size_t)ln * BSTRIDE + quad * 16;  // +ct*16*BSTRIDE per tile
        #pragma unroll
        for (int ct = 0; ct < 4; ++ct) {
            const uint8_t* bh_p = bbase + (size_t)ct * 16 * BSTRIDE;
            const uint8_t* bl_p = bh_p + NCHUNK * BSTRIDE;
            f32x4_t acc0 = {0.f, 0.f, 0.f, 0.f};
            f32x4_t acc1 = {0.f, 0.f, 0.f, 0.f};
#define KSTEP(kk) { \
            bf16x8_t bh = *(const bf16x8_t*)(bh_p + kk * 64); \
            bf16x8_t bl = *(const bf16x8_t*)(bl_p + kk * 64); \
            acc0 = MFMA_BF16(ah0##kk, bh, acc0, 0, 0, 0); \
            acc0 = MFMA_BF16(al0##kk, bh, acc0, 0, 0, 0); \
            acc0 = MFMA_BF16(ah0##kk, bl, acc0, 0, 0, 0); \
            acc1 = MFMA_BF16(ah1##kk, bh, acc1, 0, 0, 0); \
            acc1 = MFMA_BF16(al1##kk, bh, acc1, 0, 0, 0); \
            acc1 = MFMA_BF16(ah1##kk, bl, acc1, 0, 0, 0); }
            KSTEP(0) KSTEP(1) KSTEP(2) KSTEP(3)
#undef KSTEP
            const float cqv = s_cq[ct * 16 + ln];
            const int   kc  = kbase + ct * 16 + ln;
#define UPD(g,r) { \
            float s_ = fmaf(-2.0f, (g ? acc1 : acc0)[r], cqv); \
            bool c1_ = s_ < v1_##g##r; \
            bool c2_ = s_ < v2_##g##r; \
            v2_##g##r = c1_ ? v1_##g##r : (c2_ ? s_ : v2_##g##r); \
            k2_##g##r = c1_ ? k1_##g##r : (c2_ ? kc : k2_##g##r); \
            v1_##g##r = c1_ ? s_ : v1_##g##r; \
            k1_##g##r = c1_ ? kc : k1_##g##r; }
            SLOTS(UPD)
#undef UPD
        }
        __syncthreads();
    }

    // ---- butterfly merge across the 16 lanes of each col-group ----
    for (int m_ = 1; m_ <= 8; m_ <<= 1) {
#define MRG(g,r) { \
        float ov1 = __shfl_xor(v1_##g##r, m_, 16); int ok1 = __shfl_xor(k1_##g##r, m_, 16); \
        float ov2 = __shfl_xor(v2_##g##r, m_, 16); int ok2 = __shfl_xor(k2_##g##r, m_, 16); \
        if (ov1 < v1_##g##r || (ov1 == v1_##g##r && ok1 < k1_##g##r)) { \
            if (v1_##g##r < ov2 || (v1_##g##r == ov2 && k1_##g##r < ok2)) { v2_##g##r = v1_##g##r; k2_##g##r = k1_##g##r; } \
            else { v2_##g##r = ov2; k2_##g##r = ok2; } \
            v1_##g##r = ov1; k1_##g##r = ok1; \
        } else if (ov1 < v2_##g##r || (ov1 == v2_##g##r && ok1 < k2_##g##r)) { \
            v2_##g##r = ov1; k2_##g##r = ok1; \
        } }
        SLOTS(MRG)
#undef MRG
    }
    if (ln == 0) {
#define WRT(g,r) { int rloc = w * 32 + g * 16 + quad * 4 + r; \
        s_v1[rloc] = v1_##g##r; s_v2[rloc] = v2_##g##r; \
        s_k1[rloc] = k1_##g##r; s_k2[rloc] = k2_##g##r; }
        SLOTS(WRT)
#undef WRT
    }
    __syncthreads();

    // ---- per-row finalize: fp32 R1-order distance + fp64 near-tie re-decide ----
    if (t < ROWS_PB) {
        int rowg = rowblock + t;
        const bool valid = rowg < rows;
        rowg = valid ? rowg : rows - 1;
        float v1 = s_v1[t], v2 = s_v2[t];
        int k1 = s_k1[t], k2 = s_k2[t];
        const float* xr = x + (size_t)rowg * C;

        // rs in R1 float4 order
        float sx = 0.f, sy = 0.f, sz = 0.f, sw = 0.f;
        {
            const float4* xp = (const float4*)xr;
            #pragma unroll
            for (int i = 0; i < C / 4; ++i) {
                float4 v = xp[i];
                sx += v.x * v.x; sy += v.y * v.y;
                sz += v.z * v.z; sw += v.w * v.w;
            }
        }
        const float rs = (sx + sy) + (sz + sw);

        bool switched = false;
        double qwin = 0.0;
        if (v2 - v1 < EPS_TRIG) {
            const float* c1p = cb + (size_t)k1 * C;
            const float* c2p = cb + (size_t)k2 * C;
            double dot1 = 0.0, cq1 = 0.0, dot2 = 0.0, cq2 = 0.0;
            #pragma unroll 8
            for (int c = 0; c < C; ++c) {
                const double xc  = (double)xr[c];
                const double cv1 = (double)c1p[c];
                const double cv2 = (double)c2p[c];
                dot1 += xc * cv1;  cq1 += cv1 * cv1;
                dot2 += xc * cv2;  cq2 += cv2 * cv2;
            }
            const double q1 = cq1 - 2.0 * dot1;
            const double q2 = cq2 - 2.0 * dot2;
            if (q2 < q1 || (q2 == q1 && k2 < k1)) { k1 = k2; switched = true; qwin = q2; }
        }

        // exact fp32 distance for the final k1 (R1 chain order)
        const float* c1p = cb + (size_t)k1 * C;
        float a = 0.f;
        #pragma unroll 16
        for (int c = 0; c < C; ++c) a = fmaf(xr[c], c1p[c], a);
        float d = (rs + cq[k1]) - 2.f * a;
        if (switched) d = (float)((double)rs + qwin);

        if (valid) {
            out_fidx[rowg] = (float)k1;
            out_idx[rowg]  = (float)k1;
            out_dist[rowg] = d;
        }
        s_k1[t] = k1;   // final index for the gather
    }
    __syncthreads();

    // ---- gather codes: 2 threads per row ----
    {
        const int r    = t >> 1;
        const int half = t & 1;
        const int rowg = rowblock + r;
        if (rowg < rows) {
            const int k1 = s_k1[r];
            const float4* src = (const float4*)(cb + (size_t)k1 * C) + half * 16;
            float4*       dst = (float4*)(out_codes + (size_t)rowg * C) + half * 16;
            #pragma unroll
            for (int i = 0; i < 16; ++i) dst[i] = src[i];
        }
    }
}

// ---------------- fallback (R1 kernel, needs no workspace) ----------------
__global__ __launch_bounds__(TPB, 1)
void vq_nearest_fallback(const float* __restrict__ x,
                         const float* __restrict__ cb,
                         float* __restrict__ out_codes,
                         float* __restrict__ out_fidx,
                         float* __restrict__ out_idx,
                         float* __restrict__ out_dist,
                         int rows)
{
    __shared__ float s_cbsq[KCODES];
    const int t = threadIdx.x;
    for (int k = t; k < KCODES; k += TPB) {
        const float4* cp = (const float4*)(cb + (size_t)k * C);
        float sx = 0.f, sy = 0.f, sz = 0.f, sw = 0.f;
        #pragma unroll
        for (int i = 0; i < C / 4; ++i) {
            float4 v = cp[i];
            sx += v.x * v.x; sy += v.y * v.y; sz += v.z * v.z; sw += v.w * v.w;
        }
        s_cbsq[k] = (sx + sy) + (sz + sw);
    }
    __syncthreads();
    const int row = blockIdx.x * TPB + t;
    if (row >= rows) return;
    float xr[C];
    {
        const float4* xp = (const float4*)(x + (size_t)row * C);
        #pragma unroll
        for (int i = 0; i < C / 4; ++i) {
            float4 v = xp[i];
            xr[4*i+0] = v.x; xr[4*i+1] = v.y; xr[4*i+2] = v.z; xr[4*i+3] = v.w;
        }
    }
    float rs;
    {
        float sx = 0.f, sy = 0.f, sz = 0.f, sw = 0.f;
        #pragma unroll
        for (int i = 0; i < C / 4; ++i) {
            sx += xr[4*i+0]*xr[4*i+0]; sy += xr[4*i+1]*xr[4*i+1];
            sz += xr[4*i+2]*xr[4*i+2]; sw += xr[4*i+3]*xr[4*i+3];
        }
        rs = (sx + sy) + (sz + sw);
    }
    float v1 = INFINITY, v2 = INFINITY; int k1 = 0, k2 = 0;
    #pragma unroll 1
    for (int k0 = 0; k0 < KCODES; k0 += 4) {
        const float* c0 = cb + (size_t)k0 * C;
        float a0 = 0.f, a1 = 0.f, a2 = 0.f, a3 = 0.f;
        #pragma unroll
        for (int c = 0; c < C; ++c) {
            const float xc = xr[c];
            a0 = fmaf(xc, c0[c], a0);
            a1 = fmaf(xc, c0[C + c], a1);
            a2 = fmaf(xc, c0[2*C + c], a2);
            a3 = fmaf(xc, c0[3*C + c], a3);
        }
        const float d0 = (rs + s_cbsq[k0+0]) - 2.f * a0;
        const float d1 = (rs + s_cbsq[k0+1]) - 2.f * a1;
        const float d2 = (rs + s_cbsq[k0+2]) - 2.f * a2;
        const float d3 = (rs + s_cbsq[k0+3]) - 2.f * a3;
        #define UPDF(dv, ki)                                                 \
            if ((dv) < v1)      { v2 = v1; k2 = k1; v1 = (dv); k1 = (ki); } \
            else if ((dv) < v2) { v2 = (dv); k2 = (ki); }
        UPDF(d0, k0+0); UPDF(d1, k0+1); UPDF(d2, k0+2); UPDF(d3, k0+3);
        #undef UPDF
    }
    if (v2 - v1 < 0.125f) {
        const float* c1p = cb + (size_t)k1 * C;
        const float* c2p = cb + (size_t)k2 * C;
        double dot1 = 0.0, cq1 = 0.0, dot2 = 0.0, cq2 = 0.0;
        #pragma unroll 8
        for (int c = 0; c < C; ++c) {
            const double xc = (double)xr[c];
            const double cv1 = (double)c1p[c];
            const double cv2 = (double)c2p[c];
            dot1 += xc * cv1; cq1 += cv1 * cv1;
            dot2 += xc * cv2; cq2 += cv2 * cv2;
        }
        const double q1 = cq1 - 2.0 * dot1;
        const double q2 = cq2 - 2.0 * dot2;
        if (q2 < q1 || (q2 == q1 && k2 < k1)) { k1 = k2; v1 = (float)((double)rs + q2); }
    }
    {
        const float4* src = (const float4*)(cb + (size_t)k1 * C);
        float4* dst = (float4*)(out_codes + (size_t)row * C);
        #pragma unroll
        for (int i = 0; i < C / 4; ++i) dst[i] = src[i];
        out_fidx[row] = (float)k1;
        out_idx[row]  = (float)k1;
        out_dist[row] = v1;
    }
}

extern "C" void kernel_launch(void* const* d_in, const int* in_sizes, int n_in,
                              void* d_out, int out_size, void* d_ws, size_t ws_size,
                              hipStream_t stream) {
    const float* x  = (const float*)d_in[0];
    const float* cb = (const float*)d_in[1];
    const int rows = in_sizes[0] / C;   // 65536

    float* out       = (float*)d_out;
    float* out_codes = out;                          // rows*C
    float* out_fidx  = out + (size_t)rows * C;       // rows
    float* out_idx   = out_fidx + rows;              // rows
    float* out_dist  = out_idx + rows;               // rows

    // workspace layout
    const size_t cbh_off = 0;
    const size_t cbl_off = (size_t)KCODES * C * sizeof(uint16_t);      // 256 KB
    const size_t cq_off  = cbl_off * 2;                                // 512 KB
    const size_t need    = cq_off + KCODES * sizeof(float);

    if (ws_size >= need) {
        uint16_t* cbh = (uint16_t*)((char*)d_ws + cbh_off);
        uint16_t* cbl = (uint16_t*)((char*)d_ws + cbl_off);
        float*    cq  = (float*)((char*)d_ws + cq_off);

        cb_split_kernel<<<(KCODES * C + TPB - 1) / TPB, TPB, 0, stream>>>(cb, cbh, cbl);
        cbsq_kernel<<<(KCODES + TPB - 1) / TPB, TPB, 0, stream>>>(cb, cq);

        const int grid = (rows + ROWS_PB - 1) / ROWS_PB;   // 512
        vq_mfma_kernel<<<grid, TPB, 0, stream>>>(x, cb, cbh, cbl, cq,
                                                 out_codes, out_fidx, out_idx,
                                                 out_dist, rows);
    } else {
        const int rowblocks = (rows + TPB - 1) / TPB;
        vq_nearest_fallback<<<rowblocks, TPB, 0, stream>>>(x, cb, out_codes, out_fidx,
                                                           out_idx, out_dist, rows);
    }
}

// Round 2
// 164.637 us; speedup vs baseline: 1.0611x; 1.0611x over previous
//
#include <hip/hip_runtime.h>
#include <math.h>
#include <stdint.h>

#define C        128
#define KCODES   1024
#define TPB      256
#define ROWS_PB  128                  // rows per block
#define NCHUNK   64                   // codes per LDS chunk
#define NCHUNKS  (KCODES / NCHUNK)    // 16
#define BSTRIDE  272                  // padded row stride (bytes) = 128*2 + 16
#define BHALF    (NCHUNK * BSTRIDE)   // byte offset of the LO plane within a buffer
#define BUFBYTES (2 * BHALF)          // one B buffer (hi+lo) = 34816 B
#define EPS_TRIG 0.25f

typedef __attribute__((ext_vector_type(8))) short bf16x8_t;
typedef __attribute__((ext_vector_type(4))) float f32x4_t;

static __device__ __forceinline__ uint32_t bf16_rne(float f) {
    uint32_t u = __float_as_uint(f);
    return (u + 0x7FFFu + ((u >> 16) & 1u)) >> 16;
}
static __device__ __forceinline__ float bf16_hi_f(float f) {
    return __uint_as_float(bf16_rne(f) << 16);
}

// ---------------- prep (fused): split codebook into bf16 hi/lo + ||c||^2 ----------------
// NOTE: arithmetic order of both parts is IDENTICAL to the previous separate kernels
// (absmax 0.0 depends on it).
__global__ void cb_prep_kernel(const float* __restrict__ cb,
                               uint16_t* __restrict__ cbh,
                               uint16_t* __restrict__ cbl,
                               float* __restrict__ cbsq) {
    const int i = blockIdx.x * blockDim.x + threadIdx.x;
    if (i < KCODES * C) {
        float f = cb[i];
        uint32_t h = bf16_rne(f);
        float lo = f - __uint_as_float(h << 16);
        cbh[i] = (uint16_t)h;
        cbl[i] = (uint16_t)bf16_rne(lo);
    }
    if (i < KCODES) {
        const float4* cp = (const float4*)(cb + (size_t)i * C);
        float sx = 0.f, sy = 0.f, sz = 0.f, sw = 0.f;
        #pragma unroll
        for (int j = 0; j < C / 4; ++j) {
            float4 v = cp[j];
            sx += v.x * v.x; sy += v.y * v.y;
            sz += v.z * v.z; sw += v.w * v.w;
        }
        cbsq[i] = (sx + sy) + (sz + sw);
    }
}

// ---------------- main: MFMA distance + in-block argmin ----------------
#define SLOTS(OP) OP(0,0) OP(0,1) OP(0,2) OP(0,3) OP(1,0) OP(1,1) OP(1,2) OP(1,3)
#define MFMA_BF16 __builtin_amdgcn_mfma_f32_16x16x32_bf16

__global__ __launch_bounds__(TPB, 2)
void vq_mfma_kernel(const float* __restrict__ x,
                    const float* __restrict__ cb,
                    const uint16_t* __restrict__ cbh,
                    const uint16_t* __restrict__ cbl,
                    const float* __restrict__ cq,
                    float* __restrict__ out_codes,
                    float* __restrict__ out_fidx,
                    float* __restrict__ out_idx,
                    float* __restrict__ out_dist,
                    int rows)
{
    // double-buffered B (hi+lo) chunks; buffer 0 doubles as the A staging area
    __shared__ __align__(16) uint8_t s_buf[2 * BUFBYTES];   // 69632 B
    __shared__ float s_cq[2][NCHUNK];
    __shared__ float s_v1[ROWS_PB], s_v2[ROWS_PB];
    __shared__ int   s_k1[ROWS_PB], s_k2[ROWS_PB];

    const int t    = threadIdx.x;
    const int lane = t & 63;
    const int w    = t >> 6;       // wave 0..3
    const int ln   = lane & 15;
    const int quad = lane >> 4;
    const int rowblock = blockIdx.x * ROWS_PB;

    const uint4* cbh4 = (const uint4*)cbh;
    const uint4* cbl4 = (const uint4*)cbl;

    // staging registers for one B chunk (prefetch pipeline)
    uint4 rh0, rh1, rh2, rh3, rl0, rl1, rl2, rl3;
    float cqr = 0.f;

#define STAGE_LOAD(chn) { \
    const size_t gb = (size_t)(chn) * (NCHUNK * 16); \
    rh0 = cbh4[gb + t + 0 * TPB]; rh1 = cbh4[gb + t + 1 * TPB]; \
    rh2 = cbh4[gb + t + 2 * TPB]; rh3 = cbh4[gb + t + 3 * TPB]; \
    rl0 = cbl4[gb + t + 0 * TPB]; rl1 = cbl4[gb + t + 1 * TPB]; \
    rl2 = cbl4[gb + t + 2 * TPB]; rl3 = cbl4[gb + t + 3 * TPB]; \
    if (t < NCHUNK) cqr = cq[(chn) * NCHUNK + t]; }

#define STAGE_WRITE(bi) { \
    uint8_t* sb = s_buf + (bi) * BUFBYTES; \
    { int uid = t + 0 * TPB; uint8_t* p = sb + (uid >> 4) * BSTRIDE + (uid & 15) * 16; \
      *(uint4*)p = rh0; *(uint4*)(p + BHALF) = rl0; } \
    { int uid = t + 1 * TPB; uint8_t* p = sb + (uid >> 4) * BSTRIDE + (uid & 15) * 16; \
      *(uint4*)p = rh1; *(uint4*)(p + BHALF) = rl1; } \
    { int uid = t + 2 * TPB; uint8_t* p = sb + (uid >> 4) * BSTRIDE + (uid & 15) * 16; \
      *(uint4*)p = rh2; *(uint4*)(p + BHALF) = rl2; } \
    { int uid = t + 3 * TPB; uint8_t* p = sb + (uid >> 4) * BSTRIDE + (uid & 15) * 16; \
      *(uint4*)p = rh3; *(uint4*)(p + BHALF) = rl3; } \
    if (t < NCHUNK) s_cq[bi][t] = cqr; }

    // issue chunk-0 B loads immediately; latency hides under the A staging below
    STAGE_LOAD(0);

    // ---- stage x tile -> bf16 HI in s_buf (padded row-major) ----
    #pragma unroll 4
    for (int i = 0; i < 16; ++i) {
        int fid = t + i * TPB;            // float4 id in tile (4096)
        int row = fid >> 5;               // 0..127
        int kq  = fid & 31;               // float4 within row
        int grow = rowblock + row;
        grow = grow < rows ? grow : rows - 1;
        float4 v = ((const float4*)x)[(size_t)grow * 32 + kq];
        uint32_t p0 = bf16_rne(v.x) | (bf16_rne(v.y) << 16);
        uint32_t p1 = bf16_rne(v.z) | (bf16_rne(v.w) << 16);
        *(uint2*)(s_buf + row * BSTRIDE + kq * 8) = make_uint2(p0, p1);
    }
    __syncthreads();

    // ---- A-hi fragments -> registers (live for the whole kernel) ----
    const int arow0 = (w * 32 + ln) * BSTRIDE;        // rowgroup 0
    const int arow1 = (w * 32 + 16 + ln) * BSTRIDE;   // rowgroup 1
    bf16x8_t ah00, ah01, ah02, ah03, ah10, ah11, ah12, ah13;
    ah00 = *(const bf16x8_t*)(s_buf + arow0 + 0 * 64 + quad * 16);
    ah01 = *(const bf16x8_t*)(s_buf + arow0 + 1 * 64 + quad * 16);
    ah02 = *(const bf16x8_t*)(s_buf + arow0 + 2 * 64 + quad * 16);
    ah03 = *(const bf16x8_t*)(s_buf + arow0 + 3 * 64 + quad * 16);
    ah10 = *(const bf16x8_t*)(s_buf + arow1 + 0 * 64 + quad * 16);
    ah11 = *(const bf16x8_t*)(s_buf + arow1 + 1 * 64 + quad * 16);
    ah12 = *(const bf16x8_t*)(s_buf + arow1 + 2 * 64 + quad * 16);
    ah13 = *(const bf16x8_t*)(s_buf + arow1 + 3 * 64 + quad * 16);
    __syncthreads();

    // ---- stage x tile -> bf16 LO ----
    #pragma unroll 4
    for (int i = 0; i < 16; ++i) {
        int fid = t + i * TPB;
        int row = fid >> 5;
        int kq  = fid & 31;
        int grow = rowblock + row;
        grow = grow < rows ? grow : rows - 1;
        float4 v = ((const float4*)x)[(size_t)grow * 32 + kq];
        uint32_t p0 = bf16_rne(v.x - bf16_hi_f(v.x)) | (bf16_rne(v.y - bf16_hi_f(v.y)) << 16);
        uint32_t p1 = bf16_rne(v.z - bf16_hi_f(v.z)) | (bf16_rne(v.w - bf16_hi_f(v.w)) << 16);
        *(uint2*)(s_buf + row * BSTRIDE + kq * 8) = make_uint2(p0, p1);
    }
    __syncthreads();

    bf16x8_t al00, al01, al02, al03, al10, al11, al12, al13;
    al00 = *(const bf16x8_t*)(s_buf + arow0 + 0 * 64 + quad * 16);
    al01 = *(const bf16x8_t*)(s_buf + arow0 + 1 * 64 + quad * 16);
    al02 = *(const bf16x8_t*)(s_buf + arow0 + 2 * 64 + quad * 16);
    al03 = *(const bf16x8_t*)(s_buf + arow0 + 3 * 64 + quad * 16);
    al10 = *(const bf16x8_t*)(s_buf + arow1 + 0 * 64 + quad * 16);
    al11 = *(const bf16x8_t*)(s_buf + arow1 + 1 * 64 + quad * 16);
    al12 = *(const bf16x8_t*)(s_buf + arow1 + 2 * 64 + quad * 16);
    al13 = *(const bf16x8_t*)(s_buf + arow1 + 3 * 64 + quad * 16);
    __syncthreads();

    // chunk 0: write the prefetched registers into buffer 0
    STAGE_WRITE(0);
    __syncthreads();

    // ---- per-lane top-2 state (8 row-slots) ----
#define DECL(g,r) float v1_##g##r = INFINITY, v2_##g##r = INFINITY; int k1_##g##r = 0, k2_##g##r = 0;
    SLOTS(DECL)
#undef DECL

    #pragma unroll 1
    for (int chn = 0; chn < NCHUNKS; ++chn) {
        const int buf   = chn & 1;
        const int kbase = chn * NCHUNK;

        // issue next chunk's global loads; they land during this chunk's compute
        if (chn + 1 < NCHUNKS) STAGE_LOAD(chn + 1);

        const uint8_t* bbase = s_buf + buf * BUFBYTES + (size_t)ln * BSTRIDE + quad * 16;
        #pragma unroll
        for (int ct = 0; ct < 4; ++ct) {
            const uint8_t* bh_p = bbase + (size_t)ct * 16 * BSTRIDE;
            const uint8_t* bl_p = bh_p + BHALF;
            f32x4_t acc0 = {0.f, 0.f, 0.f, 0.f};
            f32x4_t acc1 = {0.f, 0.f, 0.f, 0.f};
#define KSTEP(kk) { \
            bf16x8_t bh = *(const bf16x8_t*)(bh_p + kk * 64); \
            bf16x8_t bl = *(const bf16x8_t*)(bl_p + kk * 64); \
            acc0 = MFMA_BF16(ah0##kk, bh, acc0, 0, 0, 0); \
            acc0 = MFMA_BF16(al0##kk, bh, acc0, 0, 0, 0); \
            acc0 = MFMA_BF16(ah0##kk, bl, acc0, 0, 0, 0); \
            acc1 = MFMA_BF16(ah1##kk, bh, acc1, 0, 0, 0); \
            acc1 = MFMA_BF16(al1##kk, bh, acc1, 0, 0, 0); \
            acc1 = MFMA_BF16(ah1##kk, bl, acc1, 0, 0, 0); }
            KSTEP(0) KSTEP(1) KSTEP(2) KSTEP(3)
#undef KSTEP
            const float cqv = s_cq[buf][ct * 16 + ln];
            const int   kc  = kbase + ct * 16 + ln;
#define UPD(g,r) { \
            float s_ = fmaf(-2.0f, (g ? acc1 : acc0)[r], cqv); \
            bool c1_ = s_ < v1_##g##r; \
            bool c2_ = s_ < v2_##g##r; \
            v2_##g##r = c1_ ? v1_##g##r : (c2_ ? s_ : v2_##g##r); \
            k2_##g##r = c1_ ? k1_##g##r : (c2_ ? kc : k2_##g##r); \
            v1_##g##r = c1_ ? s_ : v1_##g##r; \
            k1_##g##r = c1_ ? kc : k1_##g##r; }
            SLOTS(UPD)
#undef UPD
        }

        // write next chunk into the other buffer (current readers untouched),
        // then one barrier publishes it for the next iteration
        if (chn + 1 < NCHUNKS) STAGE_WRITE(buf ^ 1);
        __syncthreads();
    }

    // ---- butterfly merge across the 16 lanes of each col-group ----
    for (int m_ = 1; m_ <= 8; m_ <<= 1) {
#define MRG(g,r) { \
        float ov1 = __shfl_xor(v1_##g##r, m_, 16); int ok1 = __shfl_xor(k1_##g##r, m_, 16); \
        float ov2 = __shfl_xor(v2_##g##r, m_, 16); int ok2 = __shfl_xor(k2_##g##r, m_, 16); \
        if (ov1 < v1_##g##r || (ov1 == v1_##g##r && ok1 < k1_##g##r)) { \
            if (v1_##g##r < ov2 || (v1_##g##r == ov2 && k1_##g##r < ok2)) { v2_##g##r = v1_##g##r; k2_##g##r = k1_##g##r; } \
            else { v2_##g##r = ov2; k2_##g##r = ok2; } \
            v1_##g##r = ov1; k1_##g##r = ok1; \
        } else if (ov1 < v2_##g##r || (ov1 == v2_##g##r && ok1 < k2_##g##r)) { \
            v2_##g##r = ov1; k2_##g##r = ok1; \
        } }
        SLOTS(MRG)
#undef MRG
    }
    if (ln == 0) {
#define WRT(g,r) { int rloc = w * 32 + g * 16 + quad * 4 + r; \
        s_v1[rloc] = v1_##g##r; s_v2[rloc] = v2_##g##r; \
        s_k1[rloc] = k1_##g##r; s_k2[rloc] = k2_##g##r; }
        SLOTS(WRT)
#undef WRT
    }
    __syncthreads();

    // ---- per-row finalize: fp32 R1-order distance + fp64 near-tie re-decide ----
    if (t < ROWS_PB) {
        int rowg = rowblock + t;
        const bool valid = rowg < rows;
        rowg = valid ? rowg : rows - 1;
        float v1 = s_v1[t], v2 = s_v2[t];
        int k1 = s_k1[t], k2 = s_k2[t];
        const float* xr = x + (size_t)rowg * C;

        // rs in R1 float4 order
        float sx = 0.f, sy = 0.f, sz = 0.f, sw = 0.f;
        {
            const float4* xp = (const float4*)xr;
            #pragma unroll
            for (int i = 0; i < C / 4; ++i) {
                float4 v = xp[i];
                sx += v.x * v.x; sy += v.y * v.y;
                sz += v.z * v.z; sw += v.w * v.w;
            }
        }
        const float rs = (sx + sy) + (sz + sw);

        bool switched = false;
        double qwin = 0.0;
        if (v2 - v1 < EPS_TRIG) {
            const float* c1p = cb + (size_t)k1 * C;
            const float* c2p = cb + (size_t)k2 * C;
            double dot1 = 0.0, cq1 = 0.0, dot2 = 0.0, cq2 = 0.0;
            #pragma unroll 8
            for (int c = 0; c < C; ++c) {
                const double xc  = (double)xr[c];
                const double cv1 = (double)c1p[c];
                const double cv2 = (double)c2p[c];
                dot1 += xc * cv1;  cq1 += cv1 * cv1;
                dot2 += xc * cv2;  cq2 += cv2 * cv2;
            }
            const double q1 = cq1 - 2.0 * dot1;
            const double q2 = cq2 - 2.0 * dot2;
            if (q2 < q1 || (q2 == q1 && k2 < k1)) { k1 = k2; switched = true; qwin = q2; }
        }

        // exact fp32 distance for the final k1 (R1 chain order)
        const float* c1p = cb + (size_t)k1 * C;
        float a = 0.f;
        #pragma unroll 16
        for (int c = 0; c < C; ++c) a = fmaf(xr[c], c1p[c], a);
        float d = (rs + cq[k1]) - 2.f * a;
        if (switched) d = (float)((double)rs + qwin);

        if (valid) {
            out_fidx[rowg] = (float)k1;
            out_idx[rowg]  = (float)k1;
            out_dist[rowg] = d;
        }
        s_k1[t] = k1;   // final index for the gather
    }
    __syncthreads();

    // ---- gather codes: 2 threads per row ----
    {
        const int r    = t >> 1;
        const int half = t & 1;
        const int rowg = rowblock + r;
        if (rowg < rows) {
            const int k1 = s_k1[r];
            const float4* src = (const float4*)(cb + (size_t)k1 * C) + half * 16;
            float4*       dst = (float4*)(out_codes + (size_t)rowg * C) + half * 16;
            #pragma unroll
            for (int i = 0; i < 16; ++i) dst[i] = src[i];
        }
    }
#undef STAGE_LOAD
#undef STAGE_WRITE
}

// ---------------- fallback (R1 kernel, needs no workspace) ----------------
__global__ __launch_bounds__(TPB, 1)
void vq_nearest_fallback(const float* __restrict__ x,
                         const float* __restrict__ cb,
                         float* __restrict__ out_codes,
                         float* __restrict__ out_fidx,
                         float* __restrict__ out_idx,
                         float* __restrict__ out_dist,
                         int rows)
{
    __shared__ float s_cbsq[KCODES];
    const int t = threadIdx.x;
    for (int k = t; k < KCODES; k += TPB) {
        const float4* cp = (const float4*)(cb + (size_t)k * C);
        float sx = 0.f, sy = 0.f, sz = 0.f, sw = 0.f;
        #pragma unroll
        for (int i = 0; i < C / 4; ++i) {
            float4 v = cp[i];
            sx += v.x * v.x; sy += v.y * v.y; sz += v.z * v.z; sw += v.w * v.w;
        }
        s_cbsq[k] = (sx + sy) + (sz + sw);
    }
    __syncthreads();
    const int row = blockIdx.x * TPB + t;
    if (row >= rows) return;
    float xr[C];
    {
        const float4* xp = (const float4*)(x + (size_t)row * C);
        #pragma unroll
        for (int i = 0; i < C / 4; ++i) {
            float4 v = xp[i];
            xr[4*i+0] = v.x; xr[4*i+1] = v.y; xr[4*i+2] = v.z; xr[4*i+3] = v.w;
        }
    }
    float rs;
    {
        float sx = 0.f, sy = 0.f, sz = 0.f, sw = 0.f;
        #pragma unroll
        for (int i = 0; i < C / 4; ++i) {
            sx += xr[4*i+0]*xr[4*i+0]; sy += xr[4*i+1]*xr[4*i+1];
            sz += xr[4*i+2]*xr[4*i+2]; sw += xr[4*i+3]*xr[4*i+3];
        }
        rs = (sx + sy) + (sz + sw);
    }
    float v1 = INFINITY, v2 = INFINITY; int k1 = 0, k2 = 0;
    #pragma unroll 1
    for (int k0 = 0; k0 < KCODES; k0 += 4) {
        const float* c0 = cb + (size_t)k0 * C;
        float a0 = 0.f, a1 = 0.f, a2 = 0.f, a3 = 0.f;
        #pragma unroll
        for (int c = 0; c < C; ++c) {
            const float xc = xr[c];
            a0 = fmaf(xc, c0[c], a0);
            a1 = fmaf(xc, c0[C + c], a1);
            a2 = fmaf(xc, c0[2*C + c], a2);
            a3 = fmaf(xc, c0[3*C + c], a3);
        }
        const float d0 = (rs + s_cbsq[k0+0]) - 2.f * a0;
        const float d1 = (rs + s_cbsq[k0+1]) - 2.f * a1;
        const float d2 = (rs + s_cbsq[k0+2]) - 2.f * a2;
        const float d3 = (rs + s_cbsq[k0+3]) - 2.f * a3;
        #define UPDF(dv, ki)                                                 \
            if ((dv) < v1)      { v2 = v1; k2 = k1; v1 = (dv); k1 = (ki); } \
            else if ((dv) < v2) { v2 = (dv); k2 = (ki); }
        UPDF(d0, k0+0); UPDF(d1, k0+1); UPDF(d2, k0+2); UPDF(d3, k0+3);
        #undef UPDF
    }
    if (v2 - v1 < 0.125f) {
        const float* c1p = cb + (size_t)k1 * C;
        const float* c2p = cb + (size_t)k2 * C;
        double dot1 = 0.0, cq1 = 0.0, dot2 = 0.0, cq2 = 0.0;
        #pragma unroll 8
        for (int c = 0; c < C; ++c) {
            const double xc = (double)xr[c];
            const double cv1 = (double)c1p[c];
            const double cv2 = (double)c2p[c];
            dot1 += xc * cv1; cq1 += cv1 * cv1;
            dot2 += xc * cv2; cq2 += cv2 * cv2;
        }
        const double q1 = cq1 - 2.0 * dot1;
        const double q2 = cq2 - 2.0 * dot2;
        if (q2 < q1 || (q2 == q1 && k2 < k1)) { k1 = k2; v1 = (float)((double)rs + q2); }
    }
    {
        const float4* src = (const float4*)(cb + (size_t)k1 * C);
        float4* dst = (float4*)(out_codes + (size_t)row * C);
        #pragma unroll
        for (int i = 0; i < C / 4; ++i) dst[i] = src[i];
        out_fidx[row] = (float)k1;
        out_idx[row]  = (float)k1;
        out_dist[row] = v1;
    }
}

extern "C" void kernel_launch(void* const* d_in, const int* in_sizes, int n_in,
                              void* d_out, int out_size, void* d_ws, size_t ws_size,
                              hipStream_t stream) {
    const float* x  = (const float*)d_in[0];
    const float* cb = (const float*)d_in[1];
    const int rows = in_sizes[0] / C;   // 65536

    float* out       = (float*)d_out;
    float* out_codes = out;                          // rows*C
    float* out_fidx  = out + (size_t)rows * C;       // rows
    float* out_idx   = out_fidx + rows;              // rows
    float* out_dist  = out_idx + rows;               // rows

    // workspace layout
    const size_t cbh_off = 0;
    const size_t cbl_off = (size_t)KCODES * C * sizeof(uint16_t);      // 256 KB
    const size_t cq_off  = cbl_off * 2;                                // 512 KB
    const size_t need    = cq_off + KCODES * sizeof(float);

    if (ws_size >= need) {
        uint16_t* cbh = (uint16_t*)((char*)d_ws + cbh_off);
        uint16_t* cbl = (uint16_t*)((char*)d_ws + cbl_off);
        float*    cq  = (float*)((char*)d_ws + cq_off);

        cb_prep_kernel<<<(KCODES * C + TPB - 1) / TPB, TPB, 0, stream>>>(cb, cbh, cbl, cq);

        const int grid = (rows + ROWS_PB - 1) / ROWS_PB;   // 512
        vq_mfma_kernel<<<grid, TPB, 0, stream>>>(x, cb, cbh, cbl, cq,
                                                 out_codes, out_fidx, out_idx,
                                                 out_dist, rows);
    } else {
        const int rowblocks = (rows + TPB - 1) / TPB;
        vq_nearest_fallback<<<rowblocks, TPB, 0, stream>>>(x, cb, out_codes, out_fidx,
                                                           out_idx, out_dist, rows);
    }
}